// Round 11
// baseline (91.966 us; speedup 1.0000x reference)
//
#include <hip/hip_runtime.h>

// GAPooling: out[b,n,c] = mean_k x[b, idx[b,n,k], c]
// B=16, N=4096, K=32, C=64, fp32. idx int64-or-int32 (runtime-detected).
//
// R11 = R10 + block-level dual-pipe main.
//   prep (unchanged, 2048 blocks): idx -> u16 pack (4 MiB) + x -> bf16
//     chunk-planar transpose xbf[(b*8+ch)*4096+n] (8 MiB).
//   main, ONE launch, 768 blocks x 512 thr:
//     bid < 256: LDS-gather block (1/CU saturates the LDS pipe per R3=R5):
//       stage 64 KiB bf16 plane, gather points [1024,4096) (half-blocks of
//       1536) with 1 ds_read_b128 / neighbor (8 bf16 ch), exact unpack.
//     bid >= 256: pure-L2 block (no barrier, LDS unused): points [0,1024),
//       full 256B fp32 rows, c=lane, idx rows readfirstlane-scalarized ->
//       s_load; 32 independent row loads in flight per point, 4 pts/wave.
//     Different pipes (LDS vs VMEM/L2) -> co-resident blocks overlap (m114).
//   XCD swizzle: bid%16 = b -> bid%8 = b%8 for both block kinds.

#define BB 16
#define NN 4096
#define KK 32
#define CC 64
#define CH8 8
#define NCHUNK (CC / CH8)            // 8
#define THREADS 512
#define IDX16_ELEMS (BB * NN * KK)   // 2M u16 = 4 MiB
#define PREP_BLOCKS 2048
#define PREP_THREADS 256
#define PL2 1024                     // points via L2 pipe (per batch)
#define PLDS (NN - PL2)              // 3072 via LDS pipe
#define PHALF (PLDS / 2)             // 1536 = 3 x 512
#define LDS_BLOCKS (BB * NCHUNK * 2) // 256
#define L2_BLOCKS 512                // 32 pts/block, 4 pts/wave

__device__ __forceinline__ uint pk_bf16(float a, float b) {
    uint ua = __float_as_uint(a);
    ua = (ua + 0x7fffu + ((ua >> 16) & 1u)) >> 16;
    uint ub = __float_as_uint(b);
    ub = (ub + 0x7fffu + ((ub >> 16) & 1u)) & 0xffff0000u;
    return ua | ub;
}

__global__ __launch_bounds__(PREP_THREADS)
void prep_kernel(const float* __restrict__ x,
                 const int* __restrict__ idx32,
                 ushort* __restrict__ idx16,
                 uint4* __restrict__ xbf) {
    int vprobe = idx32[2 * (threadIdx.x & 63) + 1];
    const int is64 = (__ballot(vprobe != 0) == 0ULL) ? 1 : 0;

    const int tid = blockIdx.x * blockDim.x + threadIdx.x;
    const int stride = gridDim.x * blockDim.x;   // 524288

    if (is64) {
        const int4* __restrict__ in = (const int4*)idx32;   // 2 int64 / int4
        uint* __restrict__ o = (uint*)idx16;
        for (int i = tid; i < IDX16_ELEMS / 2; i += stride) {
            int4 v = in[i];
            o[i] = (uint)(v.x & 0xFFFF) | ((uint)(v.z & 0xFFFF) << 16);
        }
    } else {
        const int4* __restrict__ in = (const int4*)idx32;   // 4 int32 / int4
        uint2* __restrict__ o = (uint2*)idx16;
        for (int i = tid; i < IDX16_ELEMS / 4; i += stride) {
            int4 v = in[i];
            o[i] = make_uint2((uint)(v.x & 0xFFFF) | ((uint)(v.y & 0xFFFF) << 16),
                              (uint)(v.z & 0xFFFF) | ((uint)(v.w & 0xFFFF) << 16));
        }
    }

    // Transpose: unit u = row*8 + ch; 524288 units == stride.
    {
        const int u = tid;
        const int row = u >> 3;
        const int ch = u & 7;
        const int b = row >> 12;
        const int n = row & (NN - 1);
        const float4* __restrict__ x4 = (const float4*)x;
        const float4 v0 = x4[(size_t)row * (CC / 4) + ch * 2];
        const float4 v1 = x4[(size_t)row * (CC / 4) + ch * 2 + 1];
        xbf[(size_t)(b * NCHUNK + ch) * NN + n] =
            make_uint4(pk_bf16(v0.x, v0.y), pk_bf16(v0.z, v0.w),
                       pk_bf16(v1.x, v1.y), pk_bf16(v1.z, v1.w));
    }
}

__device__ __forceinline__ void acc8(float a[8], uint4 r) {
    a[0] += __uint_as_float(r.x << 16);
    a[1] += __uint_as_float(r.x & 0xffff0000u);
    a[2] += __uint_as_float(r.y << 16);
    a[3] += __uint_as_float(r.y & 0xffff0000u);
    a[4] += __uint_as_float(r.z << 16);
    a[5] += __uint_as_float(r.z & 0xffff0000u);
    a[6] += __uint_as_float(r.w << 16);
    a[7] += __uint_as_float(r.w & 0xffff0000u);
}

__global__ __launch_bounds__(THREADS, 2)
void gapool_dual_kernel(const float* __restrict__ x,
                        const ushort* __restrict__ idx16,
                        const uint4* __restrict__ xbf,
                        float* __restrict__ out) {
    __shared__ uint4 tile[NN];           // 64 KiB (unused by L2 blocks)

    const int bid = blockIdx.x;
    const int b = bid & 15;
    const int tid = threadIdx.x;
    const float s = 1.0f / KK;

    if (bid < LDS_BLOCKS) {
        // ---------------- LDS-gather block ----------------
        const int g = bid >> 4;              // 0..15
        const int chunk = g & (NCHUNK - 1);
        const int half = g >> 3;             // 0..1
        const int n0 = PL2 + half * PHALF;

        const ushort* __restrict__ idxq =
            idx16 + ((size_t)b * NN + n0) * KK;
        float* __restrict__ outq =
            out + ((size_t)b * NN + n0) * CC + chunk * CH8;
        const uint4* __restrict__ src = xbf + (size_t)(b * NCHUNK + chunk) * NN;

        // Preload iter-0 indices (hides behind staging).
        const uint4* __restrict__ ip0 = (const uint4*)(idxq + (size_t)tid * KK);
        uint4 pa = ip0[0], pb = ip0[1], pc = ip0[2], pd = ip0[3];

        for (int r = tid; r < NN; r += THREADS) tile[r] = src[r];
        __syncthreads();

        for (int p = tid; p < PHALF; p += THREADS) {
            const uint w[16] = {pa.x, pa.y, pa.z, pa.w, pb.x, pb.y, pb.z, pb.w,
                                pc.x, pc.y, pc.z, pc.w, pd.x, pd.y, pd.z, pd.w};
            if (p + THREADS < PHALF) {
                const uint4* ipn =
                    (const uint4*)(idxq + (size_t)(p + THREADS) * KK);
                pa = ipn[0]; pb = ipn[1]; pc = ipn[2]; pd = ipn[3];
            }

            float a[8] = {0.f, 0.f, 0.f, 0.f, 0.f, 0.f, 0.f, 0.f};
#pragma unroll
            for (int i = 0; i < 16; ++i) {
                acc8(a, tile[w[i] & 0xFFFFu]);
                acc8(a, tile[w[i] >> 16]);
            }

            float4* op = (float4*)(outq + (size_t)p * CC);
            op[0] = make_float4(a[0] * s, a[1] * s, a[2] * s, a[3] * s);
            op[1] = make_float4(a[4] * s, a[5] * s, a[6] * s, a[7] * s);
        }
    } else {
        // ---------------- pure-L2 block: exact fp32 full rows ----------------
        const int t = bid - LDS_BLOCKS;      // 0..511 (t&15 == b)
        const int grp = t >> 4;              // 0..31
        const int wv = __builtin_amdgcn_readfirstlane(tid >> 6);
        const int lane = tid & 63;

        const float* __restrict__ xb = x + (size_t)b * NN * CC;
        float* __restrict__ outb = out + (size_t)b * NN * CC;
        const ushort* __restrict__ idxb = idx16 + (size_t)b * NN * KK;

#pragma unroll
        for (int tt = 0; tt < 4; ++tt) {
            const int n = grp * 32 + wv * 4 + tt;        // scalar, in [0,1024)
            const uint* __restrict__ ip =
                (const uint*)(idxb + (size_t)n * KK);    // scalar -> s_load
            float acc = 0.f;
#pragma unroll
            for (int i = 0; i < 16; ++i) {
                const uint w = ip[i];
                acc += xb[((w & 0xFFFFu) << 6) + lane];
                acc += xb[((w >> 16) << 6) + lane];
            }
            outb[(size_t)n * CC + lane] = acc * s;
        }
    }
}

extern "C" void kernel_launch(void* const* d_in, const int* in_sizes, int n_in,
                              void* d_out, int out_size, void* d_ws, size_t ws_size,
                              hipStream_t stream) {
    const float* x     = (const float*)d_in[0];
    const int*   idx32 = (const int*)d_in[1];
    float*       out   = (float*)d_out;
    ushort*      idx16 = (ushort*)d_ws;                            // 4 MiB
    uint4*       xbf   = (uint4*)((char*)d_ws + IDX16_ELEMS * 2);  // 8 MiB

    prep_kernel<<<PREP_BLOCKS, PREP_THREADS, 0, stream>>>(x, idx32, idx16, xbf);

    gapool_dual_kernel<<<LDS_BLOCKS + L2_BLOCKS, THREADS, 0, stream>>>(
        x, idx16, xbf, out);
}

// Round 12
// 86.750 us; speedup vs baseline: 1.0601x; 1.0601x over previous
//
#include <hip/hip_runtime.h>

// GAPooling: out[b,n,c] = mean_k x[b, idx[b,n,k], c]
// B=16, N=4096, K=32, C=64, fp32. idx int64-or-int32 (runtime-detected).
//
// R12 = R10 (best, 87.2us) + async tile staging via global_load_lds (16B).
//   prep (2048 blocks): idx -> u16 pack (4 MiB) + x -> bf16 chunk-planar
//     transpose xbf[(b*8+ch)*4096+n] (8 MiB).
//   main: 512 blocks (2/CU), 64 KiB tile staged with
//     __builtin_amdgcn_global_load_lds (wave-uniform base + lane*16 matches
//     r = i*512 + w*64 + lane exactly); gather = 1 ds_read_b128 per neighbor
//     (8 bf16 channels); exact unpack <<16 / &0xffff0000; fp32 accumulate.
//   XCD swizzle: bid%16 = b -> bid%8 = b%8.

#define BB 16
#define NN 4096
#define KK 32
#define CC 64
#define CH8 8
#define NCHUNK (CC / CH8)            // 8
#define NQ 4                         // point quarters
#define PTS (NN / NQ)                // 1024
#define THREADS 512
#define IDX16_ELEMS (BB * NN * KK)   // 2M u16 = 4 MiB
#define PREP_BLOCKS 2048
#define PREP_THREADS 256

#define GLOBAL_AS __attribute__((address_space(1)))
#define LDS_AS    __attribute__((address_space(3)))

__device__ __forceinline__ uint pk_bf16(float a, float b) {
    uint ua = __float_as_uint(a);
    ua = (ua + 0x7fffu + ((ua >> 16) & 1u)) >> 16;
    uint ub = __float_as_uint(b);
    ub = (ub + 0x7fffu + ((ub >> 16) & 1u)) & 0xffff0000u;
    return ua | ub;
}

// Phase A: idx (int64-or-int32, ballot-detected) -> packed u16.
// Phase B: x fp32 [b][n][64] -> bf16 chunk-planar uint4 rows; one (row,ch)
// unit per thread (grid sized so units == total threads).
__global__ __launch_bounds__(PREP_THREADS)
void prep_kernel(const float* __restrict__ x,
                 const int* __restrict__ idx32,
                 ushort* __restrict__ idx16,
                 uint4* __restrict__ xbf) {
    int vprobe = idx32[2 * (threadIdx.x & 63) + 1];
    const int is64 = (__ballot(vprobe != 0) == 0ULL) ? 1 : 0;

    const int tid = blockIdx.x * blockDim.x + threadIdx.x;
    const int stride = gridDim.x * blockDim.x;   // 524288

    if (is64) {
        const int4* __restrict__ in = (const int4*)idx32;   // 2 int64 / int4
        uint* __restrict__ o = (uint*)idx16;
        for (int i = tid; i < IDX16_ELEMS / 2; i += stride) {
            int4 v = in[i];
            o[i] = (uint)(v.x & 0xFFFF) | ((uint)(v.z & 0xFFFF) << 16);
        }
    } else {
        const int4* __restrict__ in = (const int4*)idx32;   // 4 int32 / int4
        uint2* __restrict__ o = (uint2*)idx16;
        for (int i = tid; i < IDX16_ELEMS / 4; i += stride) {
            int4 v = in[i];
            o[i] = make_uint2((uint)(v.x & 0xFFFF) | ((uint)(v.y & 0xFFFF) << 16),
                              (uint)(v.z & 0xFFFF) | ((uint)(v.w & 0xFFFF) << 16));
        }
    }

    // Transpose: unit u = row*8 + ch; 16*4096*8 = 524288 units == stride.
    {
        const int u = tid;
        const int row = u >> 3;
        const int ch = u & 7;
        const int b = row >> 12;
        const int n = row & (NN - 1);
        const float4* __restrict__ x4 = (const float4*)x;
        const float4 v0 = x4[(size_t)row * (CC / 4) + ch * 2];
        const float4 v1 = x4[(size_t)row * (CC / 4) + ch * 2 + 1];
        xbf[(size_t)(b * NCHUNK + ch) * NN + n] =
            make_uint4(pk_bf16(v0.x, v0.y), pk_bf16(v0.z, v0.w),
                       pk_bf16(v1.x, v1.y), pk_bf16(v1.z, v1.w));
    }
}

__device__ __forceinline__ void acc8(float a[8], uint4 r) {
    a[0] += __uint_as_float(r.x << 16);
    a[1] += __uint_as_float(r.x & 0xffff0000u);
    a[2] += __uint_as_float(r.y << 16);
    a[3] += __uint_as_float(r.y & 0xffff0000u);
    a[4] += __uint_as_float(r.z << 16);
    a[5] += __uint_as_float(r.z & 0xffff0000u);
    a[6] += __uint_as_float(r.w << 16);
    a[7] += __uint_as_float(r.w & 0xffff0000u);
}

__global__ __launch_bounds__(THREADS, 4)
void gapool_bf16_kernel(const ushort* __restrict__ idx16,
                        const uint4* __restrict__ xbf,
                        float* __restrict__ out) {
    __shared__ uint4 tile[NN];           // 64 KiB: row n = 8 bf16 channels

    const int bid = blockIdx.x;          // g*16 + b
    const int b = bid & 15;
    const int g = bid >> 4;              // 0..31 = q*8 + chunk
    const int chunk = g & (NCHUNK - 1);
    const int q = g >> 3;
    const int tid = threadIdx.x;
    const float s = 1.0f / KK;

    const ushort* __restrict__ idxq =
        idx16 + ((size_t)b * NN + (size_t)q * PTS) * KK;
    float* __restrict__ outq =
        out + ((size_t)b * NN + (size_t)q * PTS) * CC + chunk * CH8;
    const uint4* __restrict__ src = xbf + (size_t)(b * NCHUNK + chunk) * NN;

    // Preload iter-0 indices (independent of tile; hides behind staging).
    const uint4* __restrict__ ip0 = (const uint4*)(idxq + (size_t)tid * KK);
    uint4 pa = ip0[0], pb = ip0[1], pc = ip0[2], pd = ip0[3];

    // Stage tile async: direct global->LDS, 16B per lane per instr.
    // r = i*512 + wave*64 + lane -> LDS dest = wave-uniform base + lane*16,
    // contiguous in lane order (the documented global_load_lds layout rule).
    {
        const GLOBAL_AS uint* gsrc = (const GLOBAL_AS uint*)src;
        LDS_AS uint* ltile = (LDS_AS uint*)tile;
#pragma unroll
        for (int i = 0; i < NN / THREADS; ++i) {
            const int r = i * THREADS + tid;
            __builtin_amdgcn_global_load_lds(gsrc + (size_t)r * 4,
                                             ltile + (size_t)r * 4, 16, 0, 0);
        }
    }
    __syncthreads();

    for (int p = tid; p < PTS; p += THREADS) {
        const uint w[16] = {pa.x, pa.y, pa.z, pa.w, pb.x, pb.y, pb.z, pb.w,
                            pc.x, pc.y, pc.z, pc.w, pd.x, pd.y, pd.z, pd.w};
        if (p + THREADS < PTS) {         // prefetch next iteration's idx
            const uint4* ipn =
                (const uint4*)(idxq + (size_t)(p + THREADS) * KK);
            pa = ipn[0]; pb = ipn[1]; pc = ipn[2]; pd = ipn[3];
        }

        float a[8] = {0.f, 0.f, 0.f, 0.f, 0.f, 0.f, 0.f, 0.f};
#pragma unroll
        for (int i = 0; i < 16; ++i) {
            acc8(a, tile[w[i] & 0xFFFFu]);
            acc8(a, tile[w[i] >> 16]);
        }

        float4* op = (float4*)(outq + (size_t)p * CC);
        op[0] = make_float4(a[0] * s, a[1] * s, a[2] * s, a[3] * s);
        op[1] = make_float4(a[4] * s, a[5] * s, a[6] * s, a[7] * s);
    }
}

extern "C" void kernel_launch(void* const* d_in, const int* in_sizes, int n_in,
                              void* d_out, int out_size, void* d_ws, size_t ws_size,
                              hipStream_t stream) {
    const float* x     = (const float*)d_in[0];
    const int*   idx32 = (const int*)d_in[1];
    float*       out   = (float*)d_out;
    ushort*      idx16 = (ushort*)d_ws;                            // 4 MiB
    uint4*       xbf   = (uint4*)((char*)d_ws + IDX16_ELEMS * 2);  // 8 MiB

    prep_kernel<<<PREP_BLOCKS, PREP_THREADS, 0, stream>>>(x, idx32, idx16, xbf);

    gapool_bf16_kernel<<<BB * NCHUNK * NQ, THREADS, 0, stream>>>(
        idx16, xbf, out);
}